// Round 3
// baseline (124.663 us; speedup 1.0000x reference)
//
#include <hip/hip_runtime.h>
#include <hip/hip_bf16.h>

#define ALPHA 0.2f
#define NEG_INF -9.0e15f

constexpr int N = 1024;
constexpr int F = 64;

// K1: Wh = h @ W  (per-row), e1 = Wh@a1, e2 = Wh@a2
// grid: N blocks, 64 threads (one wave)
__global__ void k1_wh(const float* __restrict__ h,
                      const float* __restrict__ W,
                      const float* __restrict__ a,
                      float* __restrict__ Wh,
                      float* __restrict__ e1,
                      float* __restrict__ e2) {
    const int i = blockIdx.x;
    const int j = threadIdx.x;  // 0..63, one wave

    __shared__ float hrow[F];
    hrow[j] = h[i * F + j];
    __syncthreads();

    float acc = 0.f;
    #pragma unroll
    for (int k = 0; k < F; ++k) {
        // lane j reads W[k*F + j] -> coalesced across the wave
        acc += hrow[k] * W[k * F + j];
    }
    Wh[i * F + j] = acc;

    float v1 = acc * a[j];
    float v2 = acc * a[F + j];
    // full-wave (64-lane) reduction
    #pragma unroll
    for (int off = 32; off > 0; off >>= 1) {
        v1 += __shfl_down(v1, off);
        v2 += __shfl_down(v2, off);
    }
    if (j == 0) {
        e1[i] = v1;
        e2[i] = v2;
    }
}

// K2: per row i: scores -> softmax -> h_prime = att @ Wh -> elu
// grid: N blocks, 256 threads (4 waves)
__global__ void k2_attn(const int* __restrict__ adj,
                        const float* __restrict__ Wh,
                        const float* __restrict__ e1,
                        const float* __restrict__ e2,
                        float* __restrict__ out) {
    const int i = blockIdx.x;
    const int t = threadIdx.x;       // 0..255
    const int wave = t >> 6;         // 0..3
    const int lane = t & 63;

    __shared__ float p[N];           // scores, then exp(scores - m)
    __shared__ float red[8];         // [0..3] wave maxes, [4..7] wave sums
    __shared__ float accs[4][F];     // per-wave partial h_prime

    const float e1i = e1[i];

    // pass 1: masked leaky-relu scores + local max
    float lmax = -3.0e38f;
    for (int j = t; j < N; j += 256) {
        float e = e1i + e2[j];
        e = (e > 0.f) ? e : ALPHA * e;
        float s = (adj[i * N + j] > 0) ? e : NEG_INF;
        p[j] = s;
        lmax = fmaxf(lmax, s);
    }
    #pragma unroll
    for (int off = 32; off > 0; off >>= 1)
        lmax = fmaxf(lmax, __shfl_down(lmax, off));
    if (lane == 0) red[wave] = lmax;
    __syncthreads();
    const float m = fmaxf(fmaxf(red[0], red[1]), fmaxf(red[2], red[3]));

    // pass 2: exponentiate + local sum (each thread touches only its own p[j])
    float lsum = 0.f;
    for (int j = t; j < N; j += 256) {
        float pe = __expf(p[j] - m);
        p[j] = pe;
        lsum += pe;
    }
    #pragma unroll
    for (int off = 32; off > 0; off >>= 1)
        lsum += __shfl_down(lsum, off);
    if (lane == 0) red[4 + wave] = lsum;
    __syncthreads();
    const float denom = red[4] + red[5] + red[6] + red[7];

    // pass 3: h_prime[i][f] = sum_j p[j] * Wh[j][f] / denom
    // wave g covers j in [g*256, g*256+256); lane f covers feature f
    const int f = lane;
    const int g = wave;
    float acc = 0.f;
    const int j0 = g * 256;
    for (int j = j0; j < j0 + 256; ++j) {
        // lanes read Wh[j*64 + 0..63] -> fully coalesced; p[j] is an LDS broadcast
        acc += p[j] * Wh[j * F + f];
    }
    accs[g][f] = acc;
    __syncthreads();

    if (t < F) {
        float hp = (accs[0][t] + accs[1][t] + accs[2][t] + accs[3][t]) / denom;
        float r = (hp > 0.f) ? hp : expm1f(hp);   // elu, alpha=1
        out[i * F + t] = r;
    }
}

extern "C" void kernel_launch(void* const* d_in, const int* in_sizes, int n_in,
                              void* d_out, int out_size, void* d_ws, size_t ws_size,
                              hipStream_t stream) {
    const float* h   = (const float*)d_in[0];
    const int*   adj = (const int*)d_in[1];
    const float* W   = (const float*)d_in[2];
    const float* a   = (const float*)d_in[3];
    float* out       = (float*)d_out;

    float* ws = (float*)d_ws;
    float* Wh = ws;                  // N*F floats
    float* e1 = ws + N * F;          // N floats
    float* e2 = ws + N * F + N;      // N floats

    k1_wh<<<N, 64, 0, stream>>>(h, W, a, Wh, e1, e2);
    k2_attn<<<N, 256, 0, stream>>>(adj, Wh, e1, e2, out);
}

// Round 4
// 75.672 us; speedup vs baseline: 1.6474x; 1.6474x over previous
//
#include <hip/hip_runtime.h>

#define ALPHA 0.2f
#define NEG_INF -9.0e15f

constexpr int N = 1024;
constexpr int F = 64;
constexpr int TI = 4;   // rows per block in k2

// K1: Wh = h @ W (row per wave), e1 = Wh@a1, e2 = Wh@a2
// grid: N/4 = 256 blocks, 256 threads (4 waves; wave w -> row blockIdx*4+w)
__global__ __launch_bounds__(256) void k1_wh(const float* __restrict__ h,
                                             const float* __restrict__ W,
                                             const float* __restrict__ a,
                                             float* __restrict__ Wh,
                                             float* __restrict__ e1,
                                             float* __restrict__ e2) {
    const int wave = threadIdx.x >> 6;
    const int lane = threadIdx.x & 63;
    const int i = blockIdx.x * 4 + wave;

    const float hv = h[i * F + lane];   // lane holds h[i][lane]
    float acc = 0.f;
    #pragma unroll
    for (int k = 0; k < F; ++k) {
        // broadcast h[i][k] from lane k; W row read coalesced across lanes
        acc += __shfl(hv, k) * W[k * F + lane];
    }
    Wh[i * F + lane] = acc;

    float v1 = acc * a[lane];
    float v2 = acc * a[F + lane];
    #pragma unroll
    for (int off = 32; off > 0; off >>= 1) {
        v1 += __shfl_down(v1, off);
        v2 += __shfl_down(v2, off);
    }
    if (lane == 0) {
        e1[i] = v1;
        e2[i] = v2;
    }
}

// K2: TI rows per block. scores -> softmax -> h_prime = att@Wh -> elu
// grid: N/TI = 256 blocks, 512 threads (8 waves)
__global__ __launch_bounds__(512) void k2_attn(const int* __restrict__ adj,
                                               const float* __restrict__ Wh,
                                               const float* __restrict__ e1,
                                               const float* __restrict__ e2,
                                               float* __restrict__ out) {
    const int i0 = blockIdx.x * TI;
    const int t = threadIdx.x;        // 0..511
    const int wave = t >> 6;          // 0..7
    const int lane = t & 63;

    __shared__ float p[TI][N];        // 16 KB: scores then exp(scores - m)
    __shared__ float e2s[N];          // 4 KB
    __shared__ float e1s[TI];
    __shared__ float redmax[8][TI];
    __shared__ float redsum[8][TI];
    __shared__ float accs[8][TI][F];  // 8 KB

    for (int j = t; j < N; j += 512) e2s[j] = e2[j];
    if (t < TI) e1s[t] = e1[i0 + t];
    __syncthreads();

    // pass 1: masked leaky-relu scores + per-row local max
    float lmax[TI];
    #pragma unroll
    for (int r = 0; r < TI; ++r) lmax[r] = -3.0e38f;
    #pragma unroll
    for (int r = 0; r < TI; ++r) {
        const float e1i = e1s[r];
        const int* arow = adj + (size_t)(i0 + r) * N;
        for (int j = t; j < N; j += 512) {
            float e = e1i + e2s[j];
            e = (e > 0.f) ? e : ALPHA * e;
            float s = (arow[j] > 0) ? e : NEG_INF;
            p[r][j] = s;
            lmax[r] = fmaxf(lmax[r], s);
        }
    }
    #pragma unroll
    for (int off = 32; off > 0; off >>= 1) {
        #pragma unroll
        for (int r = 0; r < TI; ++r)
            lmax[r] = fmaxf(lmax[r], __shfl_down(lmax[r], off));
    }
    if (lane == 0) {
        #pragma unroll
        for (int r = 0; r < TI; ++r) redmax[wave][r] = lmax[r];
    }
    __syncthreads();

    // pass 2: exp + per-row local sum (each thread re-reads only its own p[r][j])
    float m[TI], lsum[TI];
    #pragma unroll
    for (int r = 0; r < TI; ++r) {
        float mm = redmax[0][r];
        #pragma unroll
        for (int w = 1; w < 8; ++w) mm = fmaxf(mm, redmax[w][r]);
        m[r] = mm;
        lsum[r] = 0.f;
    }
    #pragma unroll
    for (int r = 0; r < TI; ++r) {
        for (int j = t; j < N; j += 512) {
            float pe = __expf(p[r][j] - m[r]);
            p[r][j] = pe;
            lsum[r] += pe;
        }
    }
    #pragma unroll
    for (int off = 32; off > 0; off >>= 1) {
        #pragma unroll
        for (int r = 0; r < TI; ++r)
            lsum[r] += __shfl_down(lsum[r], off);
    }
    if (lane == 0) {
        #pragma unroll
        for (int r = 0; r < TI; ++r) redsum[wave][r] = lsum[r];
    }
    __syncthreads();

    // pass 3: wave covers 128 j's, lane = feature f; 4 rows share each Wh load
    float a0 = 0.f, a1 = 0.f, a2 = 0.f, a3 = 0.f;
    const int j0 = wave * 128;
    for (int j = j0; j < j0 + 128; j += 4) {
        const float4 p0 = *(const float4*)&p[0][j];
        const float4 p1 = *(const float4*)&p[1][j];
        const float4 p2 = *(const float4*)&p[2][j];
        const float4 p3 = *(const float4*)&p[3][j];
        #pragma unroll
        for (int u = 0; u < 4; ++u) {
            const float whv = Wh[(size_t)(j + u) * F + lane];  // coalesced 256B/wave
            a0 += (&p0.x)[u] * whv;
            a1 += (&p1.x)[u] * whv;
            a2 += (&p2.x)[u] * whv;
            a3 += (&p3.x)[u] * whv;
        }
    }
    accs[wave][0][lane] = a0;
    accs[wave][1][lane] = a1;
    accs[wave][2][lane] = a2;
    accs[wave][3][lane] = a3;
    __syncthreads();

    // epilogue: reduce 8 waves, divide, ELU, store
    if (t < TI * F) {
        const int r = t >> 6;
        const int f = t & 63;
        float s = 0.f;
        #pragma unroll
        for (int w = 0; w < 8; ++w) s += accs[w][r][f];
        float dn = 0.f;
        #pragma unroll
        for (int w = 0; w < 8; ++w) dn += redsum[w][r];
        const float hp = s / dn;
        out[(size_t)(i0 + r) * F + f] = (hp > 0.f) ? hp : expm1f(hp);
    }
}

extern "C" void kernel_launch(void* const* d_in, const int* in_sizes, int n_in,
                              void* d_out, int out_size, void* d_ws, size_t ws_size,
                              hipStream_t stream) {
    const float* h   = (const float*)d_in[0];
    const int*   adj = (const int*)d_in[1];
    const float* W   = (const float*)d_in[2];
    const float* a   = (const float*)d_in[3];
    float* out       = (float*)d_out;

    float* ws = (float*)d_ws;
    float* Wh = ws;                  // N*F floats
    float* e1 = ws + N * F;          // N floats
    float* e2 = ws + N * F + N;      // N floats

    k1_wh<<<N / 4, 256, 0, stream>>>(h, W, a, Wh, e1, e2);
    k2_attn<<<N / TI, 512, 0, stream>>>(adj, Wh, e1, e2, out);
}